// Round 7
// baseline (579.392 us; speedup 1.0000x reference)
//
#include <hip/hip_runtime.h>
#include <hip/hip_bf16.h>
#include <cstdint>

typedef __attribute__((ext_vector_type(4))) float f32x4;
typedef __attribute__((ext_vector_type(4))) int i32x4;

#define IN_F 4096
#define OUT_F 4096
#define N_TOK 8192
#define NUM_FREQ 16
#define RROWS 4  // W rows per block (amortizes per-column cosines 4x)

// ---------- helpers ----------

__device__ inline float fast_tanh(float x) {
    float ax = fabsf(x);
    float e = __expf(2.0f * ax);
    float t = 1.0f - 2.0f / (e + 1.0f);
    return copysignf(t, x);
}

__device__ inline void load_lds16(const void* g, void* l) {
    __builtin_amdgcn_global_load_lds(
        (const __attribute__((address_space(1))) void*)(uintptr_t)g,
        (__attribute__((address_space(3))) void*)(uint32_t)(uintptr_t)l,
        16, 0, 0);
}

__device__ inline int q8(float v, float s) {
    int q = (int)rintf(v * s);
    return min(127, max(-127, q));
}

__device__ inline unsigned int pack4(int q0, int q1, int q2, int q3) {
    return (q0 & 255) | ((q1 & 255) << 8) | ((q2 & 255) << 16) |
           ((q3 & 255) << 24);
}

// ---------- kernel 1: fused W synthesis->i8 + x quantize->i8 ----------
// (unchanged from round 3 — verified passing)
__global__ __launch_bounds__(256)
void prep(const float* __restrict__ x, signed char* __restrict__ xq,
          float* __restrict__ sx, const float* __restrict__ amp,
          const float* __restrict__ rf, const float* __restrict__ cf,
          const float* __restrict__ rp, const float* __restrict__ cp,
          const float* __restrict__ lA, const float* __restrict__ lB,
          const float* __restrict__ alpha, const float* __restrict__ beta,
          signed char* __restrict__ wq, float* __restrict__ sw) {
    const int tid = threadIdx.x;
    const int wave = tid >> 6;
    const int lane = tid & 63;
    __shared__ float s_s[RROWS][NUM_FREQ];
    __shared__ float red[RROWS][4];

    if (blockIdx.x < OUT_F / RROWS) {
        const int o0 = blockIdx.x * RROWS;
        const float step = 6.28318530717958647692f / 4095.0f;
        if (tid < RROWS * NUM_FREQ) {
            const int r = tid >> 4;
            const int k = tid & 15;
            s_s[r][k] =
                amp[k] * __sinf(step * (float)(o0 + r) * rf[k] + rp[k]);
        }
        __syncthreads();

        const int g = lane >> 2;   // element sub-index within 16-group
        const int q = lane & 3;    // freq quad owned by this lane

        float cfr[4], cpr[4];
#pragma unroll
        for (int e = 0; e < 4; ++e) {
            cfr[e] = cf[q * 4 + e];
            cpr[e] = cp[q * 4 + e];
        }
        float skr[RROWS][4];
#pragma unroll
        for (int r = 0; r < RROWS; ++r)
#pragma unroll
            for (int e = 0; e < 4; ++e) skr[r][e] = s_s[r][q * 4 + e];

        const float sa = 1.0f / (1.0f + __expf(-alpha[0]));
        const float sb = 1.0f / (1.0f + __expf(-beta[0]));
        const float stdv = 0.015625f;  // sqrt(2/8192) = 1/64 exactly
        float a0r[RROWS], a1r[RROWS];
#pragma unroll
        for (int r = 0; r < RROWS; ++r) {
            a0r[r] = lA[(o0 + r) * 2 + 0];
            a1r[r] = lA[(o0 + r) * 2 + 1];
        }

        const int ibw = wave * 1024;
        float w[RROWS][16];

#pragma unroll
        for (int j = 0; j < 16; ++j) {
#pragma unroll
            for (int sq = 0; sq < 4; ++sq) {
                const int i = ibw + (j * 4 + sq) * 16 + g;
                const float ci = step * (float)i;
                float cv[4];
#pragma unroll
                for (int e = 0; e < 4; ++e)
                    cv[e] = __cosf(ci * cfr[e] + cpr[e]);
#pragma unroll
                for (int r = 0; r < RROWS; ++r) {
                    float p = skr[r][0] * cv[0] + skr[r][1] * cv[1] +
                              skr[r][2] * cv[2] + skr[r][3] * cv[3];
                    p += __shfl_xor(p, 1);
                    p += __shfl_xor(p, 2);
                    if (q == sq) w[r][j] = p;
                }
            }
        }

#pragma unroll
        for (int j = 0; j < 16; ++j) {
            const int i = ibw + (j * 4 + q) * 16 + g;
            const float b0 = lB[i];
            const float b1 = lB[IN_F + i];
#pragma unroll
            for (int r = 0; r < RROWS; ++r) {
                const float wl = a0r[r] * b0 + a1r[r] * b1;
                w[r][j] = sa * stdv * fast_tanh(w[r][j]) +
                          sb * stdv * fast_tanh(wl);
            }
        }

        float m[RROWS];
#pragma unroll
        for (int r = 0; r < RROWS; ++r) {
            float mm = 0.0f;
#pragma unroll
            for (int j = 0; j < 16; ++j) mm = fmaxf(mm, fabsf(w[r][j]));
#pragma unroll
            for (int off = 32; off > 0; off >>= 1)
                mm = fmaxf(mm, __shfl_xor(mm, off));
            m[r] = mm;
        }
        if (lane == 0) {
#pragma unroll
            for (int r = 0; r < RROWS; ++r) red[r][wave] = m[r];
        }
        __syncthreads();
#pragma unroll
        for (int r = 0; r < RROWS; ++r) {
            float mm = fmaxf(fmaxf(red[r][0], red[r][1]),
                             fmaxf(red[r][2], red[r][3]));
            m[r] = fmaxf(mm, 1e-20f);
        }

#pragma unroll
        for (int r = 0; r < RROWS; ++r) {
            const float s = 127.0f / m[r];
            signed char* wrow = wq + (size_t)(o0 + r) * IN_F;
#pragma unroll
            for (int j = 0; j < 16; ++j) {
                const int i = ibw + (j * 4 + q) * 16 + g;
                wrow[i] = (signed char)q8(w[r][j], s);
            }
        }
        if (tid == 0) {
#pragma unroll
            for (int r = 0; r < RROWS; ++r) sw[o0 + r] = m[r] / 127.0f;
        }
    } else {
        const int t = blockIdx.x - OUT_F / RROWS;
        const f32x4* xr = (const f32x4*)(x + (size_t)t * IN_F);
        f32x4 v[4];
#pragma unroll
        for (int j = 0; j < 4; ++j) v[j] = xr[tid + 256 * j];
        float m = 0.0f;
#pragma unroll
        for (int j = 0; j < 4; ++j)
#pragma unroll
            for (int e = 0; e < 4; ++e) m = fmaxf(m, fabsf(v[j][e]));
#pragma unroll
        for (int off = 32; off > 0; off >>= 1)
            m = fmaxf(m, __shfl_xor(m, off));
        if (lane == 0) red[0][wave] = m;
        __syncthreads();
        m = fmaxf(fmaxf(red[0][0], red[0][1]), fmaxf(red[0][2], red[0][3]));
        m = fmaxf(m, 1e-20f);
        const float s = 127.0f / m;
        unsigned int* orow = (unsigned int*)(xq + (size_t)t * IN_F);
#pragma unroll
        for (int j = 0; j < 4; ++j)
            orow[tid + 256 * j] =
                pack4(q8(v[j][0], s), q8(v[j][1], s), q8(v[j][2], s),
                      q8(v[j][3], s));
        if (tid == 0) sx[t] = m / 127.0f;
    }
}

// ---------- kernel 2: i8 MFMA GEMM — A direct-to-reg, B-only LDS ----------
// Round-7. Evidence: 3 different sync schedules all = 162us = full serial
// sum of pipe work (MFMA 1306 + LDS 1408 + ovh per slice). So: REMOVE LDS
// work instead of rearranging it.
//  - A-frags load GLOBAL->VGPR directly (natural layout: lane(quad,lm)
//    reads row bm+wm+i*16+lm, bytes [t*64+quad*16,+16) = 16 full 64B
//    lines/op). Double-buffered afA/afB (static idx), issued 1 slice
//    ahead; compiler-auto counted vmcnt covers the RAW dep. A-panel
//    slices are L1/L2-resident (8KB per wm, 4x reuse).
//  - LDS holds only B: ring of 4 x 16KB slots (64KB), same verified
//    XOR-swizzle staging (involution => both A and B deliver natural
//    quad columns; layouts consistent).
//  - ONE barrier per slice. Explicit B-ledger vmcnt at slice top:
//    bundle/slice = [8 A-loads, 2 B-stages] (order pinned by
//    sched_barrier). S(t) in bundle t-3 => steady vmcnt(20); t=0: 12
//    (prologue [S0,S1,S2,A0]); t=NT-2: 18; t=NT-1: 16. Reorders only
//    make waits stricter, never unsafe.
// Serialized LDS work/slice: 1408 -> ~512 cyc < MFMA 1306. Predicted
// gemm ~105us, MfmaUtil 55-65%.
#define BM 256
#define BN 256
#define SUBK 64

__global__ __launch_bounds__(512, 2)
void gemm_i8(const signed char* __restrict__ A, const signed char* __restrict__ B,
             const float* __restrict__ sx, const float* __restrict__ sw,
             const float* __restrict__ bias, float* __restrict__ C,
             int M, int N, int K) {
    __shared__ signed char ldsB[65536];  // 4 slots x 16KB

    const int tid = threadIdx.x;
    const int wave = tid >> 6;
    const int lane = tid & 63;

    const int bm = blockIdx.y * BM;
    const int bn = blockIdx.x * BN;

    // ---- B staging (global_load_lds, swizzled source, linear dest) ----
    const int srow = lane >> 2;
    const int scol = (((lane & 3) ^ ((lane >> 3) & 3)) << 4);
    const signed char* gB = B + (size_t)(bn + wave * 16 + srow) * K + scol;
    const size_t rowK128 = (size_t)128 * K;

    auto SB = [&](int slot, int tt) {
        signed char* lb = &ldsB[(slot << 14) + wave * 1024];
        load_lds16(gB + (size_t)tt * SUBK, lb);
        load_lds16(gB + rowK128 + (size_t)tt * SUBK, lb + 8192);
    };

    // ---- fragment addressing ----
    const int lm = lane & 15;
    const int quad = lane >> 4;
    const int kq = ((quad ^ ((lm >> 1) & 3)) << 4);  // B read swizzle
    const int wm = (wave & 1) * 128;
    const int wn = (wave >> 1) * 64;
    const int boff = (wn + lm) * SUBK + kq;

    // A direct: natural (unswizzled) quad column
    const signed char* gAr = A + (size_t)(bm + wm + lm) * K + quad * 16;

    const int NT = K >> 6;  // 64 slices

    i32x4 acc[8][4] = {};
    i32x4 afA[8], afB[8], bv[4];

    // prologue: S(0),S(1),S(2) then A(0) -> afA   [order pinned]
    SB(0, 0);
    SB(1, 1);
    SB(2, 2);
    __builtin_amdgcn_sched_barrier(0);
#pragma unroll
    for (int i = 0; i < 8; ++i)
        afA[i] = *(const i32x4*)(gAr + (size_t)(i * 16) * IN_F);
    __builtin_amdgcn_sched_barrier(0);

// one 64B k-slice. CUR consumed; NXT loaded for slice T+1.
#define SLICE(T, CUR, NXT)                                                  \
    {                                                                       \
        if ((T) == 0)                                                       \
            asm volatile("s_waitcnt vmcnt(12)" ::: "memory");               \
        else if ((T) < NT - 2)                                              \
            asm volatile("s_waitcnt vmcnt(20)" ::: "memory");               \
        else if ((T) == NT - 2)                                             \
            asm volatile("s_waitcnt vmcnt(18)" ::: "memory");               \
        else                                                                \
            asm volatile("s_waitcnt vmcnt(16)" ::: "memory");               \
        __builtin_amdgcn_s_barrier();                                       \
        __builtin_amdgcn_sched_barrier(0);                                  \
        const signed char* pb_ = &ldsB[((T) & 3) << 14];                    \
        _Pragma("unroll") for (int i = 0; i < 4; ++i)                       \
            bv[i] = *(const i32x4*)(pb_ + boff + i * 1024);                 \
        __builtin_amdgcn_sched_barrier(0);                                  \
        if ((T) + 1 < NT) {                                                 \
            _Pragma("unroll") for (int i = 0; i < 8; ++i)                   \
                NXT[i] = *(const i32x4*)(gAr + (size_t)(i * 16) * IN_F +    \
                                         ((T) + 1) * SUBK);                 \
        }                                                                   \
        __builtin_amdgcn_sched_barrier(0);                                  \
        if ((T) + 3 < NT) SB(((T) + 3) & 3, (T) + 3);                       \
        __builtin_amdgcn_sched_barrier(0);                                  \
        asm volatile("s_waitcnt lgkmcnt(0)" ::: "memory");                  \
        __builtin_amdgcn_sched_barrier(0);                                  \
        __builtin_amdgcn_s_setprio(1);                                      \
        _Pragma("unroll") for (int im = 0; im < 8; ++im)                    \
            _Pragma("unroll") for (int in = 0; in < 4; ++in)                \
                acc[im][in] = __builtin_amdgcn_mfma_i32_16x16x64_i8(        \
                    CUR[im], bv[in], acc[im][in], 0, 0, 0);                 \
        __builtin_amdgcn_s_setprio(0);                                      \
    }

    for (int t = 0; t < NT; t += 2) {
        SLICE(t, afA, afB);
        SLICE(t + 1, afB, afA);
    }
#undef SLICE

    // epilogue: D layout col = lane&15, row = quad*4 + r
    float sxv[8][4];
#pragma unroll
    for (int im = 0; im < 8; ++im)
#pragma unroll
        for (int r = 0; r < 4; ++r)
            sxv[im][r] = sx[bm + wm + im * 16 + quad * 4 + r];

#pragma unroll
    for (int in = 0; in < 4; ++in) {
        const int cn = bn + wn + in * 16 + lm;
        const float bv_ = bias[cn];
        const float scw = sw[cn];
#pragma unroll
        for (int im = 0; im < 8; ++im) {
            const int rm = bm + wm + im * 16 + quad * 4;
#pragma unroll
            for (int r = 0; r < 4; ++r)
                C[(size_t)(rm + r) * N + cn] =
                    (float)acc[im][in][r] * (sxv[im][r] * scw) + bv_;
        }
    }
}

// ---------- launch ----------
extern "C" void kernel_launch(void* const* d_in, const int* in_sizes, int n_in,
                              void* d_out, int out_size, void* d_ws,
                              size_t ws_size, hipStream_t stream) {
    const float* x = (const float*)d_in[0];
    const float* amp = (const float*)d_in[1];
    const float* rf = (const float*)d_in[2];
    const float* cf = (const float*)d_in[3];
    const float* rp = (const float*)d_in[4];
    const float* cp = (const float*)d_in[5];
    const float* lA = (const float*)d_in[6];
    const float* lB = (const float*)d_in[7];
    const float* alpha = (const float*)d_in[8];
    const float* beta = (const float*)d_in[9];
    const float* bias = (const float*)d_in[10];
    float* out = (float*)d_out;

    signed char* wq = (signed char*)d_ws;                       // 16 MiB
    signed char* xq = wq + (size_t)OUT_F * IN_F;                // 32 MiB
    float* sw = (float*)(xq + (size_t)N_TOK * IN_F);            // 16 KiB
    float* sx = sw + OUT_F;                                     // 32 KiB

    prep<<<OUT_F / RROWS + N_TOK, 256, 0, stream>>>(
        x, xq, sx, amp, rf, cf, rp, cp, lA, lB, alpha, beta, wq, sw);
    gemm_i8<<<dim3(OUT_F / BN, N_TOK / BM), 512, 0, stream>>>(
        xq, wq, sx, sw, bias, out, N_TOK, OUT_F, IN_F);
}

// Round 8
// 418.421 us; speedup vs baseline: 1.3847x; 1.3847x over previous
//
#include <hip/hip_runtime.h>
#include <hip/hip_bf16.h>
#include <cstdint>

typedef __attribute__((ext_vector_type(4))) float f32x4;
typedef __attribute__((ext_vector_type(4))) int i32x4;
typedef __attribute__((ext_vector_type(16))) int i32x16;

#define IN_F 4096
#define OUT_F 4096
#define N_TOK 8192
#define NUM_FREQ 16
#define RROWS 4  // W rows per block (amortizes per-column cosines 4x)

// ---------- helpers ----------

__device__ inline float fast_tanh(float x) {
    float ax = fabsf(x);
    float e = __expf(2.0f * ax);
    float t = 1.0f - 2.0f / (e + 1.0f);
    return copysignf(t, x);
}

__device__ inline void load_lds16(const void* g, void* l) {
    __builtin_amdgcn_global_load_lds(
        (const __attribute__((address_space(1))) void*)(uintptr_t)g,
        (__attribute__((address_space(3))) void*)(uint32_t)(uintptr_t)l,
        16, 0, 0);
}

__device__ inline int q8(float v, float s) {
    int q = (int)rintf(v * s);
    return min(127, max(-127, q));
}

__device__ inline unsigned int pack4(int q0, int q1, int q2, int q3) {
    return (q0 & 255) | ((q1 & 255) << 8) | ((q2 & 255) << 16) |
           ((q3 & 255) << 24);
}

// ---------- kernel 1: fused W synthesis->i8 + x quantize->i8 ----------
// (unchanged from round 3 — verified passing)
__global__ __launch_bounds__(256)
void prep(const float* __restrict__ x, signed char* __restrict__ xq,
          float* __restrict__ sx, const float* __restrict__ amp,
          const float* __restrict__ rf, const float* __restrict__ cf,
          const float* __restrict__ rp, const float* __restrict__ cp,
          const float* __restrict__ lA, const float* __restrict__ lB,
          const float* __restrict__ alpha, const float* __restrict__ beta,
          signed char* __restrict__ wq, float* __restrict__ sw) {
    const int tid = threadIdx.x;
    const int wave = tid >> 6;
    const int lane = tid & 63;
    __shared__ float s_s[RROWS][NUM_FREQ];
    __shared__ float red[RROWS][4];

    if (blockIdx.x < OUT_F / RROWS) {
        const int o0 = blockIdx.x * RROWS;
        const float step = 6.28318530717958647692f / 4095.0f;
        if (tid < RROWS * NUM_FREQ) {
            const int r = tid >> 4;
            const int k = tid & 15;
            s_s[r][k] =
                amp[k] * __sinf(step * (float)(o0 + r) * rf[k] + rp[k]);
        }
        __syncthreads();

        const int g = lane >> 2;   // element sub-index within 16-group
        const int q = lane & 3;    // freq quad owned by this lane

        float cfr[4], cpr[4];
#pragma unroll
        for (int e = 0; e < 4; ++e) {
            cfr[e] = cf[q * 4 + e];
            cpr[e] = cp[q * 4 + e];
        }
        float skr[RROWS][4];
#pragma unroll
        for (int r = 0; r < RROWS; ++r)
#pragma unroll
            for (int e = 0; e < 4; ++e) skr[r][e] = s_s[r][q * 4 + e];

        const float sa = 1.0f / (1.0f + __expf(-alpha[0]));
        const float sb = 1.0f / (1.0f + __expf(-beta[0]));
        const float stdv = 0.015625f;  // sqrt(2/8192) = 1/64 exactly
        float a0r[RROWS], a1r[RROWS];
#pragma unroll
        for (int r = 0; r < RROWS; ++r) {
            a0r[r] = lA[(o0 + r) * 2 + 0];
            a1r[r] = lA[(o0 + r) * 2 + 1];
        }

        const int ibw = wave * 1024;
        float w[RROWS][16];

#pragma unroll
        for (int j = 0; j < 16; ++j) {
#pragma unroll
            for (int sq = 0; sq < 4; ++sq) {
                const int i = ibw + (j * 4 + sq) * 16 + g;
                const float ci = step * (float)i;
                float cv[4];
#pragma unroll
                for (int e = 0; e < 4; ++e)
                    cv[e] = __cosf(ci * cfr[e] + cpr[e]);
#pragma unroll
                for (int r = 0; r < RROWS; ++r) {
                    float p = skr[r][0] * cv[0] + skr[r][1] * cv[1] +
                              skr[r][2] * cv[2] + skr[r][3] * cv[3];
                    p += __shfl_xor(p, 1);
                    p += __shfl_xor(p, 2);
                    if (q == sq) w[r][j] = p;
                }
            }
        }

#pragma unroll
        for (int j = 0; j < 16; ++j) {
            const int i = ibw + (j * 4 + q) * 16 + g;
            const float b0 = lB[i];
            const float b1 = lB[IN_F + i];
#pragma unroll
            for (int r = 0; r < RROWS; ++r) {
                const float wl = a0r[r] * b0 + a1r[r] * b1;
                w[r][j] = sa * stdv * fast_tanh(w[r][j]) +
                          sb * stdv * fast_tanh(wl);
            }
        }

        float m[RROWS];
#pragma unroll
        for (int r = 0; r < RROWS; ++r) {
            float mm = 0.0f;
#pragma unroll
            for (int j = 0; j < 16; ++j) mm = fmaxf(mm, fabsf(w[r][j]));
#pragma unroll
            for (int off = 32; off > 0; off >>= 1)
                mm = fmaxf(mm, __shfl_xor(mm, off));
            m[r] = mm;
        }
        if (lane == 0) {
#pragma unroll
            for (int r = 0; r < RROWS; ++r) red[r][wave] = m[r];
        }
        __syncthreads();
#pragma unroll
        for (int r = 0; r < RROWS; ++r) {
            float mm = fmaxf(fmaxf(red[r][0], red[r][1]),
                             fmaxf(red[r][2], red[r][3]));
            m[r] = fmaxf(mm, 1e-20f);
        }

#pragma unroll
        for (int r = 0; r < RROWS; ++r) {
            const float s = 127.0f / m[r];
            signed char* wrow = wq + (size_t)(o0 + r) * IN_F;
#pragma unroll
            for (int j = 0; j < 16; ++j) {
                const int i = ibw + (j * 4 + q) * 16 + g;
                wrow[i] = (signed char)q8(w[r][j], s);
            }
        }
        if (tid == 0) {
#pragma unroll
            for (int r = 0; r < RROWS; ++r) sw[o0 + r] = m[r] / 127.0f;
        }
    } else {
        const int t = blockIdx.x - OUT_F / RROWS;
        const f32x4* xr = (const f32x4*)(x + (size_t)t * IN_F);
        f32x4 v[4];
#pragma unroll
        for (int j = 0; j < 4; ++j) v[j] = xr[tid + 256 * j];
        float m = 0.0f;
#pragma unroll
        for (int j = 0; j < 4; ++j)
#pragma unroll
            for (int e = 0; e < 4; ++e) m = fmaxf(m, fabsf(v[j][e]));
#pragma unroll
        for (int off = 32; off > 0; off >>= 1)
            m = fmaxf(m, __shfl_xor(m, off));
        if (lane == 0) red[0][wave] = m;
        __syncthreads();
        m = fmaxf(fmaxf(red[0][0], red[0][1]), fmaxf(red[0][2], red[0][3]));
        m = fmaxf(m, 1e-20f);
        const float s = 127.0f / m;
        unsigned int* orow = (unsigned int*)(xq + (size_t)t * IN_F);
#pragma unroll
        for (int j = 0; j < 4; ++j)
            orow[tid + 256 * j] =
                pack4(q8(v[j][0], s), q8(v[j][1], s), q8(v[j][2], s),
                      q8(v[j][3], s));
        if (tid == 0) sx[t] = m / 127.0f;
    }
}

// ---------- kernel 2: i8 MFMA GEMM (round-3 skeleton + 2 changes) --------
// R4-R7 evidence: schedule variants, conflict removal, fetch reduction,
// occupancy changes ALL leave gemm at exactly 162us -> the binding term is
// the MFMA stream itself plus L2 locality. Round-8 changes vs round-3:
//  1. MFMA 16x16x64 -> 32x32x32 i8 (ubench 4404 vs 3944 TOPS; instr count
//     halves at identical LDS traffic). Same stored LDS layout + swizzle:
//     read position = 16(row&1)+4(unit^swz); 64 lanes cover all 8 bank
//     positions at multiplicity 8 == the verified 16x16 pattern -> expect
//     SQ_LDS_BANK_CONFLICT ~= 0. i32 accumulation is order-exact ->
//     absmax must stay EXACTLY 0.01074219 (correctness tripwire).
//  2. Bijective XCD swizzle (T1): 1024 blocks % 8 == 0 ->
//     sid=(id&7)*128+(id>>3), bn-fastest, so each XCD keeps one 1MB
//     A-panel L2-hot across 32 consecutive blocks.
// Schedule: plain 2-barrier (all fancy variants measured neutral).
#define BM 256
#define BN 128
#define BKB 128
#define SUBK 64

__global__ __launch_bounds__(256, 2)
void gemm_i8(const signed char* __restrict__ A, const signed char* __restrict__ B,
             const float* __restrict__ sx, const float* __restrict__ sw,
             const float* __restrict__ bias, float* __restrict__ C,
             int M, int N, int K) {
    __shared__ signed char sA[2][BM * SUBK];  // 2 x 16 KB
    __shared__ signed char sB[2][BN * SUBK];  // 2 x 8 KB

    const int tid = threadIdx.x;
    const int wave = tid >> 6;
    const int lane = tid & 63;

    // XCD-aware bijective remap (grid 32x32 = 1024, 8 XCDs, 128 each)
    const int id = blockIdx.y * 32 + blockIdx.x;
    const int sid = (id & 7) * 128 + (id >> 3);
    const int bm = (sid >> 5) * BM;  // bm band slow within an XCD chunk
    const int bn = (sid & 31) * BN;  // bn fastest -> A-panel stays L2-hot

    // staging: one call = 16 rows x 64B (1KB, linear in LDS dest).
    // lane l -> row l>>2, source 16B-unit = (l&3) ^ ((l>>3)&3)  [swizzle]
    const int srow = lane >> 2;
    const int scol = (((lane & 3) ^ ((lane >> 3) & 3)) << 4);

    const signed char* gA = A + (size_t)(bm + wave * 16 + srow) * K + scol;
    const signed char* gB = B + (size_t)(bn + wave * 16 + srow) * K + scol;
    const size_t rowK = (size_t)64 * K;

    // ---- 32x32x32 fragment addressing ----
    // lane: r32 = row/col within 32-tile, l5 = k-half selector
    // A frag (mt, ks): row = wm + mt*32 + r32, stored unit =
    //   (((ks<<1)|l5) ^ ((r32>>1)&3)), 16B each. Mirror for B.
    const int r32 = lane & 31;
    const int l5 = lane >> 5;
    const int swz = (lane >> 1) & 3;  // ((r32)>>1)&3

    const int wm = (wave & 1) * 128;  // wave M offset (4 tiles of 32)
    const int wn = (wave >> 1) * 64;  // wave N offset (2 tiles of 32)

    int au[2][2], bu[2][2];  // byte column offsets per ks for unit calc
#pragma unroll
    for (int ks = 0; ks < 2; ++ks) {
        au[ks][0] = ((((ks << 1) | l5) ^ swz) << 4);
        bu[ks][0] = au[ks][0];
    }

    i32x16 acc[4][2] = {};

    for (int k0 = 0; k0 < K; k0 += BKB) {
#pragma unroll
        for (int h = 0; h < 2; ++h) {
            const int kk = k0 + h * SUBK;
#pragma unroll
            for (int c = 0; c < 4; ++c)
                load_lds16(gA + (size_t)c * rowK + kk,
                           &sA[h][(wave * 16 + c * 64) * SUBK]);
#pragma unroll
            for (int c = 0; c < 2; ++c)
                load_lds16(gB + (size_t)c * rowK + kk,
                           &sB[h][(wave * 16 + c * 64) * SUBK]);
        }
        __syncthreads();

#pragma unroll
        for (int h = 0; h < 2; ++h) {
            i32x4 af[4][2], bv[2][2];
#pragma unroll
            for (int mt = 0; mt < 4; ++mt)
#pragma unroll
                for (int ks = 0; ks < 2; ++ks)
                    af[mt][ks] = *(const i32x4*)&sA[h][(wm + mt * 32 + r32) *
                                                           SUBK +
                                                       au[ks][0]];
#pragma unroll
            for (int nt = 0; nt < 2; ++nt)
#pragma unroll
                for (int ks = 0; ks < 2; ++ks)
                    bv[nt][ks] = *(const i32x4*)&sB[h][(wn + nt * 32 + r32) *
                                                           SUBK +
                                                       bu[ks][0]];

#pragma unroll
            for (int mt = 0; mt < 4; ++mt)
#pragma unroll
                for (int nt = 0; nt < 2; ++nt)
#pragma unroll
                    for (int ks = 0; ks < 2; ++ks)
                        acc[mt][nt] = __builtin_amdgcn_mfma_i32_32x32x32_i8(
                            af[mt][ks], bv[nt][ks], acc[mt][nt], 0, 0, 0);
        }

        __syncthreads();
    }

    // epilogue: 32x32 D layout col = r32, row = (reg&3) + 8*(reg>>2) + 4*l5
    float sxr[4][16];
#pragma unroll
    for (int mt = 0; mt < 4; ++mt)
#pragma unroll
        for (int c = 0; c < 4; ++c)
#pragma unroll
            for (int e = 0; e < 4; ++e)
                sxr[mt][c * 4 + e] =
                    sx[bm + wm + mt * 32 + 8 * c + 4 * l5 + e];

#pragma unroll
    for (int nt = 0; nt < 2; ++nt) {
        const int cn = bn + wn + nt * 32 + r32;
        const float bb = bias[cn];
        const float scw = sw[cn];
#pragma unroll
        for (int mt = 0; mt < 4; ++mt) {
#pragma unroll
            for (int c = 0; c < 4; ++c)
#pragma unroll
                for (int e = 0; e < 4; ++e) {
                    const int row = bm + wm + mt * 32 + 8 * c + 4 * l5 + e;
                    C[(size_t)row * N + cn] =
                        (float)acc[mt][nt][c * 4 + e] *
                            (sxr[mt][c * 4 + e] * scw) +
                        bb;
                }
        }
    }
}

// ---------- launch ----------
extern "C" void kernel_launch(void* const* d_in, const int* in_sizes, int n_in,
                              void* d_out, int out_size, void* d_ws,
                              size_t ws_size, hipStream_t stream) {
    const float* x = (const float*)d_in[0];
    const float* amp = (const float*)d_in[1];
    const float* rf = (const float*)d_in[2];
    const float* cf = (const float*)d_in[3];
    const float* rp = (const float*)d_in[4];
    const float* cp = (const float*)d_in[5];
    const float* lA = (const float*)d_in[6];
    const float* lB = (const float*)d_in[7];
    const float* alpha = (const float*)d_in[8];
    const float* beta = (const float*)d_in[9];
    const float* bias = (const float*)d_in[10];
    float* out = (float*)d_out;

    signed char* wq = (signed char*)d_ws;                       // 16 MiB
    signed char* xq = wq + (size_t)OUT_F * IN_F;                // 32 MiB
    float* sw = (float*)(xq + (size_t)N_TOK * IN_F);            // 16 KiB
    float* sx = sw + OUT_F;                                     // 32 KiB

    prep<<<OUT_F / RROWS + N_TOK, 256, 0, stream>>>(
        x, xq, sx, amp, rf, cf, rp, cp, lA, lB, alpha, beta, wq, sw);
    gemm_i8<<<dim3(OUT_F / BN, N_TOK / BM), 256, 0, stream>>>(
        xq, wq, sx, sw, bias, out, N_TOK, OUT_F, IN_F);
}